// Round 3
// baseline (788.428 us; speedup 1.0000x reference)
//
#include <hip/hip_runtime.h>
#include <math.h>

#define Bsz 8
#define Dd  128
#define Tt  4096
#define Kk  1024
#define NQ  8
#define BT  (Bsz*Tt)        // 32768 points
#define MT  128             // points per block (8 waves x 16)
#define NTHR 512
#define WV  8
#define DELTA 0.05f         // >= 10x rigorous |approx-exact| score bound

typedef float f32x4 __attribute__((ext_vector_type(4)));
typedef short short8 __attribute__((ext_vector_type(8)));

__device__ __forceinline__ unsigned short f2bf(float x) {   // RNE f32->bf16
    unsigned u = __float_as_uint(x);
    u += 0x7FFF + ((u >> 16) & 1);
    return (unsigned short)(u >> 16);
}
__device__ __forceinline__ float bf2f(unsigned short h) {
    return __uint_as_float(((unsigned)h) << 16);
}

// ---------------------------------------------------------------------------
// init: transpose x (B,D,T) -> resid (B,T,D)
// ---------------------------------------------------------------------------
__global__ void k_init(const float* __restrict__ x,
                       float* __restrict__ resid) {
    __shared__ float tile[32][33];
    int b  = blockIdx.z;
    int t0 = blockIdx.x * 32, d0 = blockIdx.y * 32;
    int tx = threadIdx.x, ty = threadIdx.y;   // 32 x 8
    #pragma unroll
    for (int k = 0; k < 4; k++) {
        int d = d0 + ty + k * 8;
        tile[ty + k * 8][tx] = x[((size_t)(b * Dd + d)) * Tt + t0 + tx];
    }
    __syncthreads();
    #pragma unroll
    for (int k = 0; k < 4; k++) {
        int t = t0 + ty + k * 8;
        resid[((size_t)(b * Tt + t)) * Dd + d0 + tx] = tile[tx][ty + k * 8];
    }
}

// ---------------------------------------------------------------------------
// k_prep: split codebook into hi/lo bf16, pre-swizzled into MFMA B-fragment
// order. B-frag (16x16x32 bf16): lane holds col n=lane&15, k=quad*8+j.
// Layout per (q, tile): 8192 B = [ch kc0..3 (1KB each) | cl kc0..3].
// ---------------------------------------------------------------------------
__global__ void k_prep(const float* __restrict__ cb, char* __restrict__ bswz) {
    int ln = threadIdx.x;                 // 64
    int kc = blockIdx.x & 3;
    int t  = (blockIdx.x >> 2) & 63;
    int q  = blockIdx.x >> 8;
    int code = t * 16 + (ln & 15);
    int d0   = kc * 32 + (ln >> 4) * 8;
    const float* src = cb + ((size_t)(q * Kk + code)) * Dd + d0;
    float v[8];
    *(float4*)&v[0] = *(const float4*)src;
    *(float4*)&v[4] = *(const float4*)(src + 4);
    short8 h, l;
    #pragma unroll
    for (int j = 0; j < 8; j++) {
        unsigned short hu = f2bf(v[j]);
        h[j] = (short)hu;
        l[j] = (short)f2bf(v[j] - bf2f(hu));   // exact remainder, then RNE
    }
    char* base = bswz + ((size_t)(q * 64 + t)) * 8192;
    *(short8*)(base + kc * 1024 + ln * 16) = h;
    *(short8*)(base + 4096 + kc * 1024 + ln * 16) = l;
}

// ---------------------------------------------------------------------------
// c2[q][k] = sum_d cb[q][k][d]^2 (exact f32) ; zero commit accumulators
// ---------------------------------------------------------------------------
__global__ void k_c2(const float* __restrict__ cb,
                     float* __restrict__ c2,
                     double* __restrict__ commits) {
    int row  = blockIdx.x * 4 + (threadIdx.x >> 6);
    int lane = threadIdx.x & 63;
    const float* p = cb + (size_t)row * Dd;
    float a = p[lane], b = p[lane + 64];
    float s = a * a + b * b;
    #pragma unroll
    for (int off = 32; off; off >>= 1) s += __shfl_down(s, off);
    if (lane == 0) c2[row] = s;
    if (blockIdx.x == 0 && threadIdx.x < NQ) commits[threadIdx.x] = 0.0;
}

// exact f32 chain, d ascending, rlds XOR-swizzled row — numeric order
// identical to the validated version (same fma sequence).
__device__ __forceinline__ float exact_score_sw(const float* __restrict__ rldsb,
                                                int p,
                                                const float* __restrict__ crow,
                                                float c2v) {
    const f32x4* r4 = (const f32x4*)rldsb;
    const f32x4* c4 = (const f32x4*)crow;
    int rb = p * 32, sw = p & 7;
    float a = 0.0f;
    #pragma unroll
    for (int d4 = 0; d4 < 32; d4++) {
        f32x4 r = r4[rb + (d4 ^ sw)];
        f32x4 c = c4[d4];
        a = fmaf(r[0], c[0], a); a = fmaf(r[1], c[1], a);
        a = fmaf(r[2], c[2], a); a = fmaf(r[3], c[3], a);
    }
    return fmaf(-2.0f, a, c2v);
}

// ---------------------------------------------------------------------------
// Fused persistent RVQ. 256 blocks x 512 thr (8 waves x 16 points), r1
// structure + 2-deep accumulator pipeline: MFMAs of tile t overlap the
// top-3 VALU of tile t-1 (named accE/accO, even/odd unrolled pair loop).
// rlds XOR-swizzled (validated r2). Staging = register->ds_write (r1,
// known-good codegen). Approx scores bit-identical to r1 (same MFMA
// summation order, same top-3 comparator) -> certification unchanged.
// ---------------------------------------------------------------------------
__global__ __launch_bounds__(NTHR, 2) void k_rvq_fused(
        float* __restrict__ resid,         // in: initial (B,T,D); out: final
        const float* __restrict__ cb,      // (NQ,K,D) f32
        const char*  __restrict__ bswz,    // (NQ*64 tiles) * 8192 B
        const float* __restrict__ c2g,     // (NQ,K) exact f32
        float* __restrict__ codes_f,       // (NQ,BT)
        double* __restrict__ commits) {    // (NQ)
    __shared__ float rlds[MT * Dd];        // 64 KB, XOR-swizzled f32x4 rows
    __shared__ float c2s[Kk];              // 4 KB
    __shared__ f32x4 bbuf[2][512];         // 16 KB double-buffered B tile
    __shared__ float fb1[MT], fb2[MT], fb3[MT];
    __shared__ int   fi1[MT], fi2[MT];
    __shared__ int   sidxs[MT];
    __shared__ int   nfall, flist[MT];
    __shared__ float fwv[WV]; __shared__ int fwi[WV];
    __shared__ float csum[WV];

    const int tid  = threadIdx.x;
    const int w    = tid >> 6, ln = tid & 63;
    const int quad = ln >> 4,  m  = ln & 15;
    const int base = blockIdx.x * MT;
    const int prow = w * 16 + m;           // A-frag row owned by this lane

    f32x4* r4 = (f32x4*)rlds;

    // block residual -> swizzled LDS (coalesced, once)
    {
        const f32x4* src = (const f32x4*)(resid + (size_t)base * Dd);
        #pragma unroll
        for (int i = 0; i < (MT * Dd / 4) / NTHR; i++) {    // 8 iters
            int idx = tid + i * NTHR;
            int row = idx >> 5, c4 = idx & 31;
            r4[row * 32 + (c4 ^ (row & 7))] = src[idx];
        }
    }
    // prologue: stage tile 0 of stage 0
    bbuf[0][tid] = *((const f32x4*)bswz + tid);
    int par = 0;
    __syncthreads();

    #pragma unroll 1
    for (int q = 0; q < NQ; q++) {
        const float* cbq = cb + (size_t)q * Kk * Dd;
        #pragma unroll
        for (int i = 0; i < Kk / NTHR; i++)                 // 2 iters
            c2s[tid + i * NTHR] = c2g[q * Kk + tid + i * NTHR];
        if (tid == 0) nfall = 0;

        // A-fragments from swizzled rlds
        short8 Ah[4], Al[4];
        #pragma unroll
        for (int kc = 0; kc < 4; kc++) {
            int c4a = kc * 8 + quad * 2;
            float v[8];
            *(f32x4*)&v[0] = r4[prow * 32 + (c4a ^ (prow & 7))];
            *(f32x4*)&v[4] = r4[prow * 32 + ((c4a + 1) ^ (prow & 7))];
            short8 h, l;
            #pragma unroll
            for (int j = 0; j < 8; j++) {
                unsigned short hu = f2bf(v[j]);
                h[j] = (short)hu;
                l[j] = (short)f2bf(v[j] - bf2f(hu));
            }
            Ah[kc] = h; Al[kc] = l;
        }

        // per-lane top-3 state (4 points per lane)
        float b1[4], b2[4], b3[4]; int i1[4], i2[4];
        #pragma unroll
        for (int j = 0; j < 4; j++) {
            b1[j] = INFINITY; b2[j] = INFINITY; b3[j] = INFINITY;
            i1[j] = 0; i2[j] = 0;
        }
        __syncthreads();   // c2s ready; bbuf[par] holds tile q*64

        // MFMA for current tile from bbuf[par] (summation order == r1)
        auto MFMA_TILE = [&](f32x4& A01, f32x4& A23) {
            const short8* Bt = (const short8*)&bbuf[par][0];
            A01 = (f32x4){0.f, 0.f, 0.f, 0.f};
            A23 = (f32x4){0.f, 0.f, 0.f, 0.f};
            __builtin_amdgcn_s_setprio(1);
            #pragma unroll
            for (int kc = 0; kc < 4; kc++) {
                short8 ch = Bt[kc * 64 + ln];
                short8 cl = Bt[256 + kc * 64 + ln];
                if (kc < 2) {
                    A01 = __builtin_amdgcn_mfma_f32_16x16x32_bf16(Al[kc], ch, A01, 0, 0, 0);
                    A01 = __builtin_amdgcn_mfma_f32_16x16x32_bf16(Ah[kc], cl, A01, 0, 0, 0);
                    A01 = __builtin_amdgcn_mfma_f32_16x16x32_bf16(Ah[kc], ch, A01, 0, 0, 0);
                } else {
                    A23 = __builtin_amdgcn_mfma_f32_16x16x32_bf16(Al[kc], ch, A23, 0, 0, 0);
                    A23 = __builtin_amdgcn_mfma_f32_16x16x32_bf16(Ah[kc], cl, A23, 0, 0, 0);
                    A23 = __builtin_amdgcn_mfma_f32_16x16x32_bf16(Ah[kc], ch, A23, 0, 0, 0);
                }
            }
            __builtin_amdgcn_s_setprio(0);
        };
        // top-3 update for tile TT (comparator/order == r1, bit-identical)
        auto SCORE = [&](const f32x4& A01, const f32x4& A23, int TT) {
            float c2v  = c2s[TT * 16 + m];
            int   code = TT * 16 + m;          // ascending per lane
            #pragma unroll
            for (int j = 0; j < 4; j++) {
                float s = fmaf(-2.0f, A01[j] + A23[j], c2v);
                bool lt1 = s < b1[j];
                bool lt2 = s < b2[j];
                b3[j] = __builtin_amdgcn_fmed3f(s, b2[j], b3[j]);
                b2[j] = __builtin_amdgcn_fmed3f(s, b1[j], b2[j]);
                i2[j] = lt1 ? i1[j] : (lt2 ? code : i2[j]);
                i1[j] = lt1 ? code : i1[j];
                b1[j] = fminf(b1[j], s);
            }
        };

        f32x4 aE01, aE23, aO01, aO23;
        #pragma unroll 1
        for (int t2 = 0; t2 < 32; t2++) {
            const int e   = 2 * t2;
            const int tte = q * 64 + e;
            // ---- even tile e ----
            f32x4 stg;
            const bool hs1 = (tte + 1 < NQ * 64);
            if (hs1)
                stg = *((const f32x4*)(bswz + (size_t)(tte + 1) * 8192) + tid);
            MFMA_TILE(aE01, aE23);                 // tile e
            if (t2 > 0) SCORE(aO01, aO23, e - 1);  // finish tile e-1
            if (hs1) bbuf[par ^ 1][tid] = stg;
            __syncthreads();
            par ^= 1;
            // ---- odd tile e+1 ----
            const int tto = tte + 1;
            const bool hs2 = (tto + 1 < NQ * 64);
            if (hs2)
                stg = *((const f32x4*)(bswz + (size_t)(tto + 1) * 8192) + tid);
            MFMA_TILE(aO01, aO23);                 // tile e+1
            SCORE(aE01, aE23, e);                  // finish tile e
            if (hs2) bbuf[par ^ 1][tid] = stg;
            __syncthreads();
            par ^= 1;
        }
        SCORE(aO01, aO23, 63);                     // epilogue: tile 63

        // cross-lane merge of sorted triples over the 16 cols (xor 1,2,4,8)
        #pragma unroll
        for (int j = 0; j < 4; j++) {
            float v1 = b1[j], v2 = b2[j], v3 = b3[j];
            int   a1 = i1[j], a2 = i2[j];
            #pragma unroll
            for (int off = 1; off < 16; off <<= 1) {
                float w1 = __shfl_xor(v1, off); int j1 = __shfl_xor(a1, off);
                float w2 = __shfl_xor(v2, off); int j2 = __shfl_xor(a2, off);
                float w3 = __shfl_xor(v3, off);
                bool aw = (v1 < w1) || (v1 == w1 && a1 < j1);
                float x1 = aw ? v1 : w1, x2 = aw ? v2 : w2, x3 = aw ? v3 : w3;
                int   y1 = aw ? a1 : j1, y2 = aw ? a2 : j2;
                float z1 = aw ? w1 : v1, z2 = aw ? w2 : v2;
                int   u1 = aw ? j1 : a1;
                bool s2a = (x2 < z1) || (x2 == z1 && y2 < u1);
                v1 = x1; a1 = y1;
                v2 = s2a ? x2 : z1; a2 = s2a ? y2 : u1;
                v3 = s2a ? fminf(x3, z1) : fminf(x2, z2);
            }
            if (m == 0) {
                int p = w * 16 + quad * 4 + j;
                fb1[p] = v1; fb2[p] = v2; fb3[p] = v3;
                fi1[p] = a1; fi2[p] = a2;
            }
        }
        __syncthreads();

        // decision + exact rescore of <=2 candidates (thread per point)
        if (tid < MT) {
            int p = tid;
            float v1 = fb1[p], v2 = fb2[p], v3 = fb3[p];
            int   a1 = fi1[p], a2 = fi2[p];
            if (v3 <= v1 + DELTA) {
                int sl = atomicAdd(&nfall, 1);     // rare: >=3 in window
                flist[sl] = p;
            } else {
                int bk = a1;
                if (v2 <= v1 + DELTA) {            // two candidates: rescore
                    float s1 = exact_score_sw(rlds, p, cbq + (size_t)a1 * Dd, c2s[a1]);
                    float s2 = exact_score_sw(rlds, p, cbq + (size_t)a2 * Dd, c2s[a2]);
                    if (s2 < s1 || (s2 == s1 && a2 < a1)) bk = a2;
                }
                sidxs[p] = bk;
                codes_f[(size_t)q * BT + base + p] = (float)bk;
            }
        }
        __syncthreads();

        // fallback: block-cooperative exact scan (executes ~never; exact)
        for (int fi = 0; fi < nfall; fi++) {
            int p = flist[fi];
            float bv = INFINITY; int bk = 0;
            #pragma unroll
            for (int c = 0; c < 2; c++) {
                int k = tid * 2 + c;               // ascending within thread
                float sc = exact_score_sw(rlds, p, cbq + (size_t)k * Dd, c2s[k]);
                if (sc < bv || (sc == bv && k < bk)) { bv = sc; bk = k; }
            }
            #pragma unroll
            for (int off = 32; off; off >>= 1) {
                float v2 = __shfl_xor(bv, off);
                int   k2 = __shfl_xor(bk, off);
                if (v2 < bv || (v2 == bv && k2 < bk)) { bv = v2; bk = k2; }
            }
            if (ln == 0) { fwv[w] = bv; fwi[w] = bk; }
            __syncthreads();
            if (tid == 0) {
                float v = fwv[0]; int k = fwi[0];
                #pragma unroll
                for (int w2 = 1; w2 < WV; w2++) {
                    if (fwv[w2] < v || (fwv[w2] == v && fwi[w2] < k)) {
                        v = fwv[w2]; k = fwi[w2];
                    }
                }
                sidxs[p] = k;
                codes_f[(size_t)q * BT + base + p] = (float)k;
            }
            __syncthreads();
        }
        __syncthreads();

        // fused STE update (swizzled rlds): thread -> point tid>>2,
        // dims [(tid&3)*32, +32). Per-element op order bit-identical.
        {
            int p = tid >> 2;
            int rb = p * 32, sw = p & 7, cb4 = (tid & 3) * 8;
            const float* qrow = cbq + ((size_t)sidxs[p]) * Dd + (tid & 3) * 32;
            float cacc = 0.0f;
            #pragma unroll
            for (int hh = 0; hh < 8; hh++) {
                f32x4 r  = r4[rb + ((cb4 + hh) ^ sw)];
                f32x4 qv = *(const f32x4*)(qrow + hh * 4);
                float t1x = qv[0] - r[0], t1y = qv[1] - r[1];
                float t1z = qv[2] - r[2], t1w = qv[3] - r[3];  // q - residual
                float qsx = r[0] + t1x, qsy = r[1] + t1y;
                float qsz = r[2] + t1z, qsw = r[3] + t1w;      // straight-through
                f32x4 nr = { r[0] - qsx, r[1] - qsy, r[2] - qsz, r[3] - qsw };
                r4[rb + ((cb4 + hh) ^ sw)] = nr;
                cacc = fmaf(t1x, t1x, cacc); cacc = fmaf(t1y, t1y, cacc);
                cacc = fmaf(t1z, t1z, cacc); cacc = fmaf(t1w, t1w, cacc);
            }
            #pragma unroll
            for (int off = 32; off; off >>= 1) cacc += __shfl_down(cacc, off);
            if (ln == 0) csum[w] = cacc;
        }
        __syncthreads();
        if (tid == 0) {
            double sd = 0.0;
            #pragma unroll
            for (int w2 = 0; w2 < WV; w2++) sd += (double)csum[w2];
            atomicAdd(commits + q, sd);
        }
        __syncthreads();   // gates next stage's c2s overwrite + A-prep
    }

    // final residual back to global (coalesced, once)
    {
        f32x4* dst = (f32x4*)(resid + (size_t)base * Dd);
        #pragma unroll
        for (int i = 0; i < (MT * Dd / 4) / NTHR; i++) {
            int idx = tid + i * NTHR;
            int row = idx >> 5, c4 = idx & 31;
            dst[idx] = r4[row * 32 + (c4 ^ (row & 7))];
        }
    }
}

// ---------------------------------------------------------------------------
// final: out(B,D,T) = x - resid_final^T
// ---------------------------------------------------------------------------
__global__ void k_final(const float* __restrict__ x,
                        const float* __restrict__ resid,
                        float* __restrict__ outq) {
    __shared__ float tile[32][33];
    int b  = blockIdx.z;
    int t0 = blockIdx.x * 32, d0 = blockIdx.y * 32;
    int tx = threadIdx.x, ty = threadIdx.y;   // 32 x 8
    #pragma unroll
    for (int k = 0; k < 4; k++) {
        int t = t0 + ty + k * 8;
        tile[ty + k * 8][tx] = resid[((size_t)(b * Tt + t)) * Dd + d0 + tx];
    }
    __syncthreads();
    #pragma unroll
    for (int k = 0; k < 4; k++) {
        int d = d0 + ty + k * 8;
        size_t o = ((size_t)(b * Dd + d)) * Tt + t0 + tx;
        outq[o] = x[o] - tile[tx][ty + k * 8];
    }
}

// ---------------------------------------------------------------------------
// scalars: bw = n_q * log2(K) * frame_rate ; penalty = mean(commits)
// ---------------------------------------------------------------------------
__global__ void k_scalars(const double* __restrict__ commits,
                          const int* __restrict__ frame_rate,
                          float* __restrict__ outs) {
    if (threadIdx.x == 0 && blockIdx.x == 0) {
        double s = 0.0;
        #pragma unroll
        for (int q = 0; q < NQ; q++) s += commits[q];
        double per_elem = s / ((double)NQ * (double)BT * (double)Dd);
        outs[0] = (float)(NQ * 10.0 * (double)frame_rate[0]); // log2(1024)=10
        outs[1] = (float)per_elem;
    }
}

extern "C" void kernel_launch(void* const* d_in, const int* in_sizes, int n_in,
                              void* d_out, int out_size, void* d_ws, size_t ws_size,
                              hipStream_t stream) {
    const float* x  = (const float*)d_in[0];   // (B, D, T)
    const float* cb = (const float*)d_in[1];   // (NQ, K, D)
    const int*   fr = (const int*)d_in[2];     // frame_rate

    float* outq    = (float*)d_out;                       // (B,D,T) 4194304
    float* codes_f = outq + (size_t)Bsz * Dd * Tt;        // (NQ,B,T) 262144
    float* scal    = codes_f + (size_t)NQ * BT;           // bw, penalty

    char* ws = (char*)d_ws;
    float*  resid   = (float*)ws;                              // BT*D f32
    float*  c2      = resid + (size_t)BT * Dd;                 // NQ*K f32
    double* commits = (double*)(c2 + (size_t)NQ * Kk);         // NQ f64
    char*   bswz    = (char*)(commits + NQ);                   // NQ*64*8192 B

    dim3 tb(32, 8, 1);
    k_init<<<dim3(Tt / 32, Dd / 32, Bsz), tb, 0, stream>>>(x, resid);
    k_prep<<<NQ * 256, 64, 0, stream>>>(cb, bswz);
    k_c2<<<NQ * Kk / 4, 256, 0, stream>>>(cb, c2, commits);

    k_rvq_fused<<<BT / MT, NTHR, 0, stream>>>(resid, cb, bswz, c2,
                                              codes_f, commits);

    k_final<<<dim3(Tt / 32, Dd / 32, Bsz), tb, 0, stream>>>(x, resid, outq);
    k_scalars<<<1, 64, 0, stream>>>(commits, fr, scal);
}